// Round 7
// baseline (1072.673 us; speedup 1.0000x reference)
//
#include <hip/hip_runtime.h>

#define B_ 4
#define H_ 256
#define W_ 256
#define Z_ 64
#define NB_ (H_*W_*Z_)      /* 4194304 */
#define N_  (B_*NB_)        /* 16777216 */
#define ITER_ 8
#define EPS_ 1e-6f
#define SLOTS_ 64

/* scal layout (floats) */
#define RHO_OFF   0
#define ETA_OFF   ((ITER_+1)*B_*SLOTS_)
#define LOSS_OFF  (ETA_OFF + ITER_*B_*SLOTS_)
#define MAXE_OFF  (LOSS_OFF + SLOTS_)
#define SCAL_FLOATS (MAXE_OFF + SLOTS_)

struct F8 { float4 a, b; };

__device__ __forceinline__ float wsum(float v){
  v += __shfl_xor(v,32); v += __shfl_xor(v,16); v += __shfl_xor(v,8);
  v += __shfl_xor(v,4);  v += __shfl_xor(v,2);  v += __shfl_xor(v,1);
  return v;
}
__device__ __forceinline__ float wmaxr(float v){
  v = fmaxf(v,__shfl_xor(v,32)); v = fmaxf(v,__shfl_xor(v,16));
  v = fmaxf(v,__shfl_xor(v,8));  v = fmaxf(v,__shfl_xor(v,4));
  v = fmaxf(v,__shfl_xor(v,2));  v = fmaxf(v,__shfl_xor(v,1));
  return v;
}
__device__ __forceinline__ float read_sum(const float* s){
  return wsum(s[threadIdx.x & 63]);
}
__device__ __forceinline__ void block_atomic_sum(float v, float* dst, float* lds){
  v = wsum(v);
  int wid = threadIdx.x >> 6, lane = threadIdx.x & 63;
  if (lane == 0) lds[wid] = v;
  __syncthreads();
  if (threadIdx.x == 0) atomicAdd(dst, lds[0]+lds[1]+lds[2]+lds[3]);
}

__device__ __forceinline__ float4 ld4(const float* p){ return *(const float4*)p; }

__device__ __forceinline__ void sub8(F8& s, const F8& n){
  s.a.x-=n.a.x; s.a.y-=n.a.y; s.a.z-=n.a.z; s.a.w-=n.a.w;
  s.b.x-=n.b.x; s.b.y-=n.b.y; s.b.z-=n.b.z; s.b.w-=n.b.w;
}

/* z-part of stencil: zl/zr via wave shuffle (neighbor lane's center values). */
__device__ __forceinline__ void zcore(const F8& c, int zc, F8& st){
  float zl = __shfl_up(c.b.w, 1);
  float zr = __shfl_down(c.a.x, 1);
  zl = (zc > 0) ? zl : 0.f;
  zr = (zc < 7) ? zr : 0.f;
  st.a.x = 6.f*c.a.x - zl    - c.a.y;
  st.a.y = 6.f*c.a.y - c.a.x - c.a.z;
  st.a.z = 6.f*c.a.z - c.a.y - c.a.w;
  st.a.w = 6.f*c.a.w - c.a.z - c.b.x;
  st.b.x = 6.f*c.b.x - c.a.w - c.b.y;
  st.b.y = 6.f*c.b.y - c.b.x - c.b.z;
  st.b.z = 6.f*c.b.z - c.b.y - c.b.w;
  st.b.w = 6.f*c.b.w - c.b.z - zr;
}

/* ---- 4-row stencils: rows h0..h0+3; internal h-neighbors reuse registers ---- */
__device__ __forceinline__ void stencil1_4(const float* __restrict__ a, int base0,
                                           int w, int h0, int zc,
                                           F8 c[4], F8 st[4])
{
  const int S = W_*Z_;
  #pragma unroll
  for (int k = 0; k < 4; ++k) {
    c[k].a = ld4(a+base0+k*S); c[k].b = ld4(a+base0+k*S+4);
  }
  #pragma unroll
  for (int k = 0; k < 4; ++k) zcore(c[k], zc, st[k]);
  F8 t;
  if (w > 0) {
    #pragma unroll
    for (int k = 0; k < 4; ++k) {
      t.a = ld4(a+base0+k*S-Z_); t.b = ld4(a+base0+k*S-Z_+4); sub8(st[k],t);
    }
  }
  if (w < W_-1) {
    #pragma unroll
    for (int k = 0; k < 4; ++k) {
      t.a = ld4(a+base0+k*S+Z_); t.b = ld4(a+base0+k*S+Z_+4); sub8(st[k],t);
    }
  }
  if (h0 > 0)    { t.a = ld4(a+base0-S); t.b = ld4(a+base0-S+4); sub8(st[0],t); }
  sub8(st[0], c[1]);
  sub8(st[1], c[0]); sub8(st[1], c[2]);
  sub8(st[2], c[1]); sub8(st[2], c[3]);
  sub8(st[3], c[2]);
  if (h0 < H_-4) { t.a = ld4(a+base0+4*S); t.b = ld4(a+base0+4*S+4); sub8(st[3],t); }
}

__device__ __forceinline__ F8 comb8(const float* r, const float* p, float beta, int idx){
  F8 o;
  float4 ra = ld4(r+idx), rb = ld4(r+idx+4);
  float4 pa = ld4(p+idx), pb = ld4(p+idx+4);
  o.a.x = ra.x + beta*pa.x; o.a.y = ra.y + beta*pa.y;
  o.a.z = ra.z + beta*pa.z; o.a.w = ra.w + beta*pa.w;
  o.b.x = rb.x + beta*pb.x; o.b.y = rb.y + beta*pb.y;
  o.b.z = rb.z + beta*pb.z; o.b.w = rb.w + beta*pb.w;
  return o;
}
__device__ __forceinline__ void stencil2_4(const float* __restrict__ r,
                                           const float* __restrict__ p, float beta,
                                           int base0, int w, int h0, int zc,
                                           F8 c[4], F8 st[4])
{
  const int S = W_*Z_;
  #pragma unroll
  for (int k = 0; k < 4; ++k) c[k] = comb8(r,p,beta,base0+k*S);
  #pragma unroll
  for (int k = 0; k < 4; ++k) zcore(c[k], zc, st[k]);
  if (w > 0) {
    #pragma unroll
    for (int k = 0; k < 4; ++k) sub8(st[k], comb8(r,p,beta,base0+k*S-Z_));
  }
  if (w < W_-1) {
    #pragma unroll
    for (int k = 0; k < 4; ++k) sub8(st[k], comb8(r,p,beta,base0+k*S+Z_));
  }
  if (h0 > 0)    sub8(st[0], comb8(r,p,beta,base0-S));
  sub8(st[0], c[1]);
  sub8(st[1], c[0]); sub8(st[1], c[2]);
  sub8(st[2], c[1]); sub8(st[2], c[3]);
  sub8(st[3], c[2]);
  if (h0 < H_-4) sub8(st[3], comb8(r,p,beta,base0+4*S));
}

/* ---- 2-row stencil (kept for k_fin2) ---- */
__device__ __forceinline__ void stencil1_2(const float* __restrict__ a, int base0,
                                           int w, int h0, int zc,
                                           F8& c0, F8& c1, F8& st0, F8& st1)
{
  const int base1 = base0 + W_*Z_;
  c0.a = ld4(a+base0); c0.b = ld4(a+base0+4);
  c1.a = ld4(a+base1); c1.b = ld4(a+base1+4);
  zcore(c0, zc, st0);
  zcore(c1, zc, st1);
  F8 t;
  if (w > 0)    { t.a = ld4(a+base0-Z_); t.b = ld4(a+base0-Z_+4); sub8(st0,t);
                  t.a = ld4(a+base1-Z_); t.b = ld4(a+base1-Z_+4); sub8(st1,t); }
  if (w < W_-1) { t.a = ld4(a+base0+Z_); t.b = ld4(a+base0+Z_+4); sub8(st0,t);
                  t.a = ld4(a+base1+Z_); t.b = ld4(a+base1+Z_+4); sub8(st1,t); }
  if (h0 > 0)   { t.a = ld4(a+base0-W_*Z_); t.b = ld4(a+base0-W_*Z_+4); sub8(st0,t); }
  sub8(st0, c1);
  sub8(st1, c0);
  if (h0 < H_-2){ t.a = ld4(a+base1+W_*Z_); t.b = ld4(a+base1+W_*Z_+4); sub8(st1,t); }
}

__device__ __forceinline__ float dot8(const F8& a, const F8& b){
  return a.a.x*b.a.x + a.a.y*b.a.y + a.a.z*b.a.z + a.a.w*b.a.w
       + a.b.x*b.b.x + a.b.y*b.b.y + a.b.z*b.b.z + a.b.w*b.b.w;
}

#define IDX4_SETUP \
  const int zc = threadIdx.x & 7; \
  const int wl = threadIdx.x >> 3; \
  const int w  = blockIdx.x*32 + wl; \
  const int h0 = blockIdx.y*4; \
  const int bb = blockIdx.z; \
  const int base0 = ((bb*H_ + h0)*W_ + w)*Z_ + zc*8; \
  const int flat = (blockIdx.z*gridDim.y + blockIdx.y)*gridDim.x + blockIdx.x; \
  const int slot = flat & (SLOTS_-1);

#define IDX2_SETUP \
  const int zc = threadIdx.x & 7; \
  const int wl = threadIdx.x >> 3; \
  const int w  = blockIdx.x*32 + wl; \
  const int h0 = blockIdx.y*2; \
  const int bb = blockIdx.z; \
  const int base0 = ((bb*H_ + h0)*W_ + w)*Z_ + zc*8; \
  const int flat = (blockIdx.z*gridDim.y + blockIdx.y)*gridDim.x + blockIdx.x; \
  const int slot = flat & (SLOTS_-1);

/* r = b - A x ; rho0 = <r,r> per batch (4 rows/thread) */
__global__ __launch_bounds__(256) void k_init4(const float* __restrict__ x,
                                               const float* __restrict__ b,
                                               float* __restrict__ r,
                                               float* scal)
{
  __shared__ float lds[4];
  IDX4_SETUP
  const int S = W_*Z_;
  F8 c[4], st[4];
  stencil1_4(x, base0, w, h0, zc, c, st);
  float rho = 0.f;
  #pragma unroll
  for (int k = 0; k < 4; ++k) {
    float4 b0 = ld4(b+base0+k*S), b1 = ld4(b+base0+k*S+4);
    F8 rv;
    rv.a = make_float4(b0.x-st[k].a.x, b0.y-st[k].a.y, b0.z-st[k].a.z, b0.w-st[k].a.w);
    rv.b = make_float4(b1.x-st[k].b.x, b1.y-st[k].b.y, b1.z-st[k].b.z, b1.w-st[k].b.w);
    *(float4*)(r+base0+k*S)   = rv.a;
    *(float4*)(r+base0+k*S+4) = rv.b;
    rho += dot8(rv,rv);
  }
  block_atomic_sum(rho, scal + RHO_OFF + (0*B_+bb)*SLOTS_ + slot, lds);
}

/* it==0: eta0 = <r, A r>; optional p0 = r copy (fallback path only) */
__global__ __launch_bounds__(256) void k_a0_4(const float* __restrict__ r,
                                              float* __restrict__ pnew,
                                              float* scal)
{
  __shared__ float lds[4];
  IDX4_SETUP
  const int S = W_*Z_;
  F8 c[4], st[4];
  stencil1_4(r, base0, w, h0, zc, c, st);
  float eta = 0.f;
  #pragma unroll
  for (int k = 0; k < 4; ++k) eta += dot8(c[k], st[k]);
  if (pnew) {
    #pragma unroll
    for (int k = 0; k < 4; ++k) {
      *(float4*)(pnew+base0+k*S)   = c[k].a;
      *(float4*)(pnew+base0+k*S+4) = c[k].b;
    }
  }
  block_atomic_sum(eta, scal + ETA_OFF + (0*B_+bb)*SLOTS_ + slot, lds);
}

/* it>=1: p_new = r + beta*p_old ; eta = <p_new, A p_new> (4 rows/thread) */
__global__ __launch_bounds__(256) void k_a4(const float* __restrict__ r,
                                            const float* __restrict__ pold,
                                            float* __restrict__ pnew,
                                            float* scal, int it)
{
  __shared__ float lds[4];
  IDX4_SETUP
  const int S = W_*Z_;
  float num = read_sum(scal + RHO_OFF + (it*B_+bb)*SLOTS_);
  float den = read_sum(scal + RHO_OFF + ((it-1)*B_+bb)*SLOTS_);
  float beta = num / (den + EPS_);
  F8 c[4], st[4];
  stencil2_4(r, pold, beta, base0, w, h0, zc, c, st);
  float eta = 0.f;
  #pragma unroll
  for (int k = 0; k < 4; ++k) {
    *(float4*)(pnew+base0+k*S)   = c[k].a;
    *(float4*)(pnew+base0+k*S+4) = c[k].b;
    eta += dot8(c[k], st[k]);
  }
  block_atomic_sum(eta, scal + ETA_OFF + (it*B_+bb)*SLOTS_ + slot, lds);
}

/* even it: NO x update (deferred); r_out = r_in - alpha*A p; rho_next */
__global__ __launch_bounds__(256) void k_b4_nox(const float* r_in,
                                                float* r_out,
                                                const float* p,
                                                float* scal, int it)
{
  __shared__ float lds[4];
  IDX4_SETUP
  const int S = W_*Z_;
  float num = read_sum(scal + RHO_OFF + (it*B_+bb)*SLOTS_);
  float den = read_sum(scal + ETA_OFF + (it*B_+bb)*SLOTS_);
  float alpha = num / (den + EPS_);
  F8 c[4], st[4];
  stencil1_4(p, base0, w, h0, zc, c, st);
  float rho = 0.f;
  #pragma unroll
  for (int k = 0; k < 4; ++k) {
    float4 r0 = ld4(r_in+base0+k*S), r1 = ld4(r_in+base0+k*S+4);
    r0.x -= alpha*st[k].a.x; r0.y -= alpha*st[k].a.y; r0.z -= alpha*st[k].a.z; r0.w -= alpha*st[k].a.w;
    r1.x -= alpha*st[k].b.x; r1.y -= alpha*st[k].b.y; r1.z -= alpha*st[k].b.z; r1.w -= alpha*st[k].b.w;
    *(float4*)(r_out+base0+k*S)   = r0;
    *(float4*)(r_out+base0+k*S+4) = r1;
    rho += r0.x*r0.x + r0.y*r0.y + r0.z*r0.z + r0.w*r0.w
         + r1.x*r1.x + r1.y*r1.y + r1.z*r1.z + r1.w*r1.w;
  }
  block_atomic_sum(rho, scal + RHO_OFF + ((it+1)*B_+bb)*SLOTS_ + slot, lds);
}

/* odd it<7: x += alpha_prev*p_prev + alpha*p; r_out = r_in - alpha*A p; rho */
__global__ __launch_bounds__(256) void k_b4_pair(float* __restrict__ x,
                                                 const float* r_in,
                                                 float* r_out,
                                                 const float* p,
                                                 const float* __restrict__ pprev,
                                                 float* scal, int it)
{
  __shared__ float lds[4];
  IDX4_SETUP
  const int S = W_*Z_;
  float num = read_sum(scal + RHO_OFF + (it*B_+bb)*SLOTS_);
  float den = read_sum(scal + ETA_OFF + (it*B_+bb)*SLOTS_);
  float alpha = num / (den + EPS_);
  float nump = read_sum(scal + RHO_OFF + ((it-1)*B_+bb)*SLOTS_);
  float denp = read_sum(scal + ETA_OFF + ((it-1)*B_+bb)*SLOTS_);
  float alphap = nump / (denp + EPS_);
  F8 c[4], st[4];
  stencil1_4(p, base0, w, h0, zc, c, st);
  float rho = 0.f;
  #pragma unroll
  for (int k = 0; k < 4; ++k) {
    const int bk = base0 + k*S;
    float4 q0 = ld4(pprev+bk), q1 = ld4(pprev+bk+4);
    float4 x0 = ld4(x+bk), x1 = ld4(x+bk+4);
    x0.x += alphap*q0.x + alpha*c[k].a.x; x0.y += alphap*q0.y + alpha*c[k].a.y;
    x0.z += alphap*q0.z + alpha*c[k].a.z; x0.w += alphap*q0.w + alpha*c[k].a.w;
    x1.x += alphap*q1.x + alpha*c[k].b.x; x1.y += alphap*q1.y + alpha*c[k].b.y;
    x1.z += alphap*q1.z + alpha*c[k].b.z; x1.w += alphap*q1.w + alpha*c[k].b.w;
    *(float4*)(x+bk)   = x0;
    *(float4*)(x+bk+4) = x1;
    float4 r0 = ld4(r_in+bk), r1 = ld4(r_in+bk+4);
    r0.x -= alpha*st[k].a.x; r0.y -= alpha*st[k].a.y; r0.z -= alpha*st[k].a.z; r0.w -= alpha*st[k].a.w;
    r1.x -= alpha*st[k].b.x; r1.y -= alpha*st[k].b.y; r1.z -= alpha*st[k].b.z; r1.w -= alpha*st[k].b.w;
    *(float4*)(r_out+bk)   = r0;
    *(float4*)(r_out+bk+4) = r1;
    rho += r0.x*r0.x + r0.y*r0.y + r0.z*r0.z + r0.w*r0.w
         + r1.x*r1.x + r1.y*r1.y + r1.z*r1.z + r1.w*r1.w;
  }
  block_atomic_sum(rho, scal + RHO_OFF + ((it+1)*B_+bb)*SLOTS_ + slot, lds);
}

/* fallback-path k_b (x updated every iteration, 4 rows) */
__global__ __launch_bounds__(256) void k_b4(float* __restrict__ x,
                                            const float* r_in,
                                            float* r_out,
                                            const float* p,
                                            float* scal, int it)
{
  __shared__ float lds[4];
  IDX4_SETUP
  const int S = W_*Z_;
  float num = read_sum(scal + RHO_OFF + (it*B_+bb)*SLOTS_);
  float den = read_sum(scal + ETA_OFF + (it*B_+bb)*SLOTS_);
  float alpha = num / (den + EPS_);
  F8 c[4], st[4];
  stencil1_4(p, base0, w, h0, zc, c, st);
  float rho = 0.f;
  #pragma unroll
  for (int k = 0; k < 4; ++k) {
    const int bk = base0 + k*S;
    float4 x0 = ld4(x+bk), x1 = ld4(x+bk+4);
    x0.x += alpha*c[k].a.x; x0.y += alpha*c[k].a.y; x0.z += alpha*c[k].a.z; x0.w += alpha*c[k].a.w;
    x1.x += alpha*c[k].b.x; x1.y += alpha*c[k].b.y; x1.z += alpha*c[k].b.z; x1.w += alpha*c[k].b.w;
    *(float4*)(x+bk)   = x0;
    *(float4*)(x+bk+4) = x1;
    float4 r0 = ld4(r_in+bk), r1 = ld4(r_in+bk+4);
    r0.x -= alpha*st[k].a.x; r0.y -= alpha*st[k].a.y; r0.z -= alpha*st[k].a.z; r0.w -= alpha*st[k].a.w;
    r1.x -= alpha*st[k].b.x; r1.y -= alpha*st[k].b.y; r1.z -= alpha*st[k].b.z; r1.w -= alpha*st[k].b.w;
    *(float4*)(r_out+bk)   = r0;
    *(float4*)(r_out+bk+4) = r1;
    rho += r0.x*r0.x + r0.y*r0.y + r0.z*r0.z + r0.w*r0.w
         + r1.x*r1.x + r1.y*r1.y + r1.z*r1.z + r1.w*r1.w;
  }
  block_atomic_sum(rho, scal + RHO_OFF + ((it+1)*B_+bb)*SLOTS_ + slot, lds);
}

/* it==7: 2-row final (unchanged from round 6) */
__global__ __launch_bounds__(256) void k_fin2(const float* __restrict__ x,
                                              const float* __restrict__ r,
                                              const float* __restrict__ p,
                                              const float* pprev,
                                              const float* __restrict__ ref,
                                              float* __restrict__ out,
                                              float* scal, int it)
{
  __shared__ float xs[4096];
  __shared__ float lds[12];
  IDX2_SETUP
  const int base1 = base0 + W_*Z_;
  const int t = threadIdx.x;
  float num = read_sum(scal + RHO_OFF + (it*B_+bb)*SLOTS_);
  float den = read_sum(scal + ETA_OFF + (it*B_+bb)*SLOTS_);
  float alpha = num / (den + EPS_);
  float alphap = 0.f;
  if (pprev) {
    float nump = read_sum(scal + RHO_OFF + ((it-1)*B_+bb)*SLOTS_);
    float denp = read_sum(scal + ETA_OFF + ((it-1)*B_+bb)*SLOTS_);
    alphap = nump / (denp + EPS_);
  }
  F8 c0,c1,st0,st1;
  stencil1_2(p, base0, w, h0, zc, c0, c1, st0, st1);

  float rho = 0.f, loss = 0.f, me = 0.f;
  float4 xa0, xa1, xb0, xb1;
  {
    xa0 = ld4(x+base0); xa1 = ld4(x+base0+4);
    if (pprev) {
      float4 q0 = ld4(pprev+base0), q1 = ld4(pprev+base0+4);
      xa0.x += alphap*q0.x; xa0.y += alphap*q0.y; xa0.z += alphap*q0.z; xa0.w += alphap*q0.w;
      xa1.x += alphap*q1.x; xa1.y += alphap*q1.y; xa1.z += alphap*q1.z; xa1.w += alphap*q1.w;
    }
    xa0.x += alpha*c0.a.x; xa0.y += alpha*c0.a.y; xa0.z += alpha*c0.a.z; xa0.w += alpha*c0.a.w;
    xa1.x += alpha*c0.b.x; xa1.y += alpha*c0.b.y; xa1.z += alpha*c0.b.z; xa1.w += alpha*c0.b.w;
    float4 r0 = ld4(r+base0), r1 = ld4(r+base0+4);
    r0.x -= alpha*st0.a.x; r0.y -= alpha*st0.a.y; r0.z -= alpha*st0.a.z; r0.w -= alpha*st0.a.w;
    r1.x -= alpha*st0.b.x; r1.y -= alpha*st0.b.y; r1.z -= alpha*st0.b.z; r1.w -= alpha*st0.b.w;
    rho += r0.x*r0.x + r0.y*r0.y + r0.z*r0.z + r0.w*r0.w
         + r1.x*r1.x + r1.y*r1.y + r1.z*r1.z + r1.w*r1.w;
    float4 f0 = ld4(ref+base0), f1 = ld4(ref+base0+4);
    float d0 = xa0.x-f0.x, d1 = xa0.y-f0.y, d2 = xa0.z-f0.z, d3 = xa0.w-f0.w;
    float d4 = xa1.x-f1.x, d5 = xa1.y-f1.y, d6 = xa1.z-f1.z, d7 = xa1.w-f1.w;
    loss += d0*d0+d1*d1+d2*d2+d3*d3+d4*d4+d5*d5+d6*d6+d7*d7;
    me = fmaxf(me, fmaxf(fmaxf(fmaxf(fabsf(d0),fabsf(d1)),fmaxf(fabsf(d2),fabsf(d3))),
                         fmaxf(fmaxf(fabsf(d4),fabsf(d5)),fmaxf(fabsf(d6),fabsf(d7)))));
  }
  {
    xb0 = ld4(x+base1); xb1 = ld4(x+base1+4);
    if (pprev) {
      float4 q0 = ld4(pprev+base1), q1 = ld4(pprev+base1+4);
      xb0.x += alphap*q0.x; xb0.y += alphap*q0.y; xb0.z += alphap*q0.z; xb0.w += alphap*q0.w;
      xb1.x += alphap*q1.x; xb1.y += alphap*q1.y; xb1.z += alphap*q1.z; xb1.w += alphap*q1.w;
    }
    xb0.x += alpha*c1.a.x; xb0.y += alpha*c1.a.y; xb0.z += alpha*c1.a.z; xb0.w += alpha*c1.a.w;
    xb1.x += alpha*c1.b.x; xb1.y += alpha*c1.b.y; xb1.z += alpha*c1.b.z; xb1.w += alpha*c1.b.w;
    float4 r0 = ld4(r+base1), r1 = ld4(r+base1+4);
    r0.x -= alpha*st1.a.x; r0.y -= alpha*st1.a.y; r0.z -= alpha*st1.a.z; r0.w -= alpha*st1.a.w;
    r1.x -= alpha*st1.b.x; r1.y -= alpha*st1.b.y; r1.z -= alpha*st1.b.z; r1.w -= alpha*st1.b.w;
    rho += r0.x*r0.x + r0.y*r0.y + r0.z*r0.z + r0.w*r0.w
         + r1.x*r1.x + r1.y*r1.y + r1.z*r1.z + r1.w*r1.w;
    float4 f0 = ld4(ref+base1), f1 = ld4(ref+base1+4);
    float d0 = xb0.x-f0.x, d1 = xb0.y-f0.y, d2 = xb0.z-f0.z, d3 = xb0.w-f0.w;
    float d4 = xb1.x-f1.x, d5 = xb1.y-f1.y, d6 = xb1.z-f1.z, d7 = xb1.w-f1.w;
    loss += d0*d0+d1*d1+d2*d2+d3*d3+d4*d4+d5*d5+d6*d6+d7*d7;
    me = fmaxf(me, fmaxf(fmaxf(fmaxf(fabsf(d0),fabsf(d1)),fmaxf(fabsf(d2),fabsf(d3))),
                         fmaxf(fmaxf(fabsf(d4),fabsf(d5)),fmaxf(fabsf(d6),fabsf(d7)))));
  }

  xs[t*8+0] = xa0.x; xs[t*8+1] = xa0.y; xs[t*8+2] = xa0.z; xs[t*8+3] = xa0.w;
  xs[t*8+4] = xa1.x; xs[t*8+5] = xa1.y; xs[t*8+6] = xa1.z; xs[t*8+7] = xa1.w;
  xs[2048+t*8+0] = xb0.x; xs[2048+t*8+1] = xb0.y; xs[2048+t*8+2] = xb0.z; xs[2048+t*8+3] = xb0.w;
  xs[2048+t*8+4] = xb1.x; xs[2048+t*8+5] = xb1.y; xs[2048+t*8+6] = xb1.z; xs[2048+t*8+7] = xb1.w;

  float rs = wsum(rho), ls = wsum(loss), ms = wmaxr(me);
  int wid = t >> 6, lane = t & 63;
  if (lane == 0) { lds[wid] = rs; lds[4+wid] = ls; lds[8+wid] = ms; }
  __syncthreads();
  if (t == 0) {
    atomicAdd(scal + RHO_OFF + ((it+1)*B_+bb)*SLOTS_ + slot, lds[0]+lds[1]+lds[2]+lds[3]);
    atomicAdd(scal + LOSS_OFF + slot, lds[4]+lds[5]+lds[6]+lds[7]);
    float bm = fmaxf(fmaxf(lds[8],lds[9]), fmaxf(lds[10],lds[11]));
    atomicMax((unsigned int*)(scal + MAXE_OFF) + slot, __float_as_uint(bm));
  }

  const int S0 = ((bb*H_ + h0)*8 + (int)blockIdx.x)*2048;
  #pragma unroll
  for (int rr = 0; rr < 2; ++rr) {
    const float* xr = xs + rr*2048;
    const int S = S0 + rr*(8*2048);
    #pragma unroll
    for (int c2 = 0; c2 < 2; ++c2) {
      int q = t + 256*c2;
      if (q < 511) {
        float4 v = make_float4(xr[3+4*q], xr[4+4*q], xr[5+4*q], xr[6+4*q]);
        *(float4*)(out + S + 4 + 4*q) = v;
      } else if (q == 511) {
        out[S+1] = xr[0]; out[S+2] = xr[1]; out[S+3] = xr[2];
        out[S+2048] = xr[2047];
      }
    }
  }
}

__global__ __launch_bounds__(64) void k_scal(const float* scal, float* out)
{
  int lane = threadIdx.x;
  float loss = wsum(scal[LOSS_OFF + lane]);
  float me   = wmaxr(__uint_as_float(((const unsigned int*)scal)[MAXE_OFF + lane]));
  float rho_sum = 0.f;
  for (int bb = 0; bb < B_; ++bb)
    rho_sum += wsum(scal[RHO_OFF + (ITER_*B_+bb)*SLOTS_ + lane]);
  if (lane == 0) {
    out[0]      = loss / (float)N_;
    out[1+N_]   = me;
    out[2+N_]   = rho_sum / (float)B_;
  }
}

extern "C" void kernel_launch(void* const* d_in, const int* in_sizes, int n_in,
                              void* d_out, int out_size, void* d_ws, size_t ws_size,
                              hipStream_t stream) {
  float* x         = (float*)d_in[0];
  const float* bv  = (const float*)d_in[1];
  const float* ref = (const float*)d_in[2];
  float* out       = (float*)d_out;
  float* ws        = (float*)d_ws;

  dim3 g4(W_/32, H_/4, B_), gF(W_/32, H_/2, B_), blk(256);
  bool fast = ws_size >= ((size_t)3*N_ + SCAL_FLOATS) * sizeof(float);
  float* scal;

  if (fast) {
    /* R0: r0/p0, then even-generation p buffer. R1: live r. P0: odd-gen p.
       Deferred x: even its skip x; odd its add alpha_{it-1}*pprev + alpha_it*pcur. */
    float* R0 = ws;
    float* R1 = ws + N_;
    float* P0 = ws + 2*(size_t)N_;
    scal = ws + 3*(size_t)N_;
    (void)hipMemsetAsync(scal, 0, SCAL_FLOATS*sizeof(float), stream);

    k_init4 <<<g4, blk, 0, stream>>>(x, bv, R0, scal);
    k_a0_4  <<<g4, blk, 0, stream>>>(R0, nullptr, scal);       /* p0 == r0 == R0 */
    k_b4_nox<<<g4, blk, 0, stream>>>(R0, R1, R0, scal, 0);     /* r1 -> R1, no x */
    for (int it = 1; it < ITER_; ++it) {
      float* pnew = (it & 1) ? P0 : R0;
      float* pold = (it & 1) ? R0 : P0;
      k_a4<<<g4, blk, 0, stream>>>(R1, pold, pnew, scal, it);
      if (it == ITER_-1)        /* it=7: pnew=P0, pprev=R0 (holds p6) */
        k_fin2<<<gF, blk, 0, stream>>>(x, R1, pnew, pold, ref, out, scal, it);
      else if (it & 1)          /* odd: apply deferred pair alpha_{it-1},alpha_it */
        k_b4_pair<<<g4, blk, 0, stream>>>(x, R1, R1, pnew, pold, scal, it);
      else                      /* even: defer x */
        k_b4_nox<<<g4, blk, 0, stream>>>(R1, R1, pnew, scal, it);
    }
  } else {
    /* fallback: r in-place in ws0; p ping-pong ws1/out; x updated every iter;
       fin (it=7) reads ws1, pprev=null -> no out aliasing. */
    float* r    = ws;
    float* p0w  = ws + N_;
    scal = ws + 2*(size_t)N_;
    (void)hipMemsetAsync(scal, 0, SCAL_FLOATS*sizeof(float), stream);

    k_init4<<<g4, blk, 0, stream>>>(x, bv, r, scal);
    k_a0_4 <<<g4, blk, 0, stream>>>(r, out, scal);             /* p0 -> out */
    k_b4   <<<g4, blk, 0, stream>>>(x, r, r, out, scal, 0);
    float* pa = p0w; float* pb = out;
    for (int it = 1; it < ITER_; ++it) {
      k_a4<<<g4, blk, 0, stream>>>(r, pb, pa, scal, it);
      if (it < ITER_-1)
        k_b4<<<g4, blk, 0, stream>>>(x, r, r, pa, scal, it);
      else
        k_fin2<<<gF, blk, 0, stream>>>(x, r, pa, nullptr, ref, out, scal, it);
      pb = pa; pa = (pa == p0w) ? out : p0w;
    }
    /* parity: it=1..7 -> pa = ws1,out,ws1,out,ws1,out,ws1 ; fin reads ws1 */
  }
  k_scal<<<1, 64, 0, stream>>>(scal, out);
}